// Round 7
// baseline (1495.645 us; speedup 1.0000x reference)
//
#include <hip/hip_runtime.h>
#include <stdint.h>

#define DEPTH 4
#define BATCH 8
#define NN 2048
#define ZDIM 512
#define SDIM 64
#define MLPD 2048
#define ROWS (BATCH*NN)   // 16384

typedef __bf16 bf16x8_t __attribute__((ext_vector_type(8)));
typedef float f32x4_t __attribute__((ext_vector_type(4)));
typedef unsigned short us;

#define AS1 __attribute__((address_space(1)))
#define AS3 __attribute__((address_space(3)))

__device__ __forceinline__ void gload16(const void* g, void* l) {
  __builtin_amdgcn_global_load_lds((const AS1 void*)g, (AS3 void*)l, 16, 0, 0);
}

__device__ __forceinline__ unsigned short f2bf(float f) {
  union { float f; unsigned u; } v; v.f = f;
  unsigned u = v.u;
  unsigned r = (u + 0x7fffu + ((u >> 16) & 1u)) >> 16;
  return (unsigned short)r;
}
__device__ __forceinline__ float bf2f(unsigned short h) {
  union { unsigned u; float f; } v; v.u = ((unsigned)h) << 16;
  return v.f;
}

// exact-erf GELU via Abramowitz-Stegun 7.1.26 (max abs err 1.5e-7)
__device__ __forceinline__ float gelu_fast(float x) {
  float ax = fabsf(x) * 0.70710678118654752440f;
  float t = __builtin_amdgcn_rcpf(1.0f + 0.3275911f * ax);
  float p = t * (0.254829592f + t * (-0.284496736f + t * (1.421413741f +
            t * (-1.453152027f + t * 1.061405429f))));
  float er = 1.0f - p * __expf(-ax * ax);
  float s = (x >= 0.f) ? er : -er;
  return 0.5f * x * (1.0f + s);
}

// ---- convert spatial embedding rows to bf16 + squared norms ------------------
__global__ __launch_bounds__(256) void conv_e_kernel(const float* __restrict__ s,
    unsigned short* __restrict__ ebf, float* __restrict__ sq) {
  int lane = threadIdx.x & 63;
  int row = blockIdx.x * 4 + (threadIdx.x >> 6);
  float x = s[(long)row * SDIM + lane];
  unsigned short v = f2bf(x);
  ebf[(long)row * SDIM + lane] = v;
  float xb = bf2f(v);
  float ss = xb * xb;
  #pragma unroll
  for (int off = 32; off > 0; off >>= 1) ss += __shfl_xor(ss, off);
  if (lane == 0) sq[row] = ss;
}

// ---- transpose + f32->bf16: in [R][C] f32 -> out [C][R] bf16, batched --------
__global__ __launch_bounds__(256) void tconv_kernel(const float* __restrict__ in,
    unsigned short* __restrict__ out, int R, int C, long sIn, long sOut) {
  __shared__ float tile[32][33];
  int b = blockIdx.z;
  int c0 = blockIdx.x * 32, r0 = blockIdx.y * 32;
  int tx = threadIdx.x, ty = threadIdx.y;
  const float* ib = in + (long)b * sIn;
  unsigned short* ob = out + (long)b * sOut;
  #pragma unroll
  for (int i = 0; i < 32; i += 8)
    tile[ty + i][tx] = ib[(long)(r0 + ty + i) * C + c0 + tx];
  __syncthreads();
  #pragma unroll
  for (int i = 0; i < 32; i += 8)
    ob[(long)(c0 + ty + i) * R + r0 + tx] = f2bf(tile[tx][ty + i]);
}

// ---- LayerNorm over D=512, write bf16 normalized rows ------------------------
__global__ __launch_bounds__(256) void ln_kernel(const float* __restrict__ x,
    const float* __restrict__ scale, const float* __restrict__ bias,
    unsigned short* __restrict__ y) {
  int lane = threadIdx.x & 63;
  long row = (long)blockIdx.x * 4 + (threadIdx.x >> 6);
  const float* xr = x + row * ZDIM + lane * 8;
  float4 v0 = *(const float4*)xr;
  float4 v1 = *(const float4*)(xr + 4);
  float xv[8] = {v0.x, v0.y, v0.z, v0.w, v1.x, v1.y, v1.z, v1.w};
  float s1 = 0.f, s2 = 0.f;
  #pragma unroll
  for (int k = 0; k < 8; ++k) { s1 += xv[k]; s2 += xv[k] * xv[k]; }
  #pragma unroll
  for (int off = 32; off > 0; off >>= 1) {
    s1 += __shfl_xor(s1, off);
    s2 += __shfl_xor(s2, off);
  }
  float mean = s1 * (1.0f / ZDIM);
  float var = s2 * (1.0f / ZDIM) - mean * mean;
  float rstd = rsqrtf(var + 1e-5f);
  const float* sc = scale + lane * 8;
  const float* bi = bias + lane * 8;
  alignas(16) unsigned short o[8];
  #pragma unroll
  for (int k = 0; k < 8; ++k)
    o[k] = f2bf((xv[k] - mean) * rstd * sc[k] + bi[k]);
  *(uint4*)(y + row * ZDIM + lane * 8) = *(const uint4*)o;
}

// ---- attention weights: w = exp(-max(sq_i+sq_j-2*e_i.e_j,0)), plus 1/rowsum --
__global__ __launch_bounds__(256) void attn_w_kernel(const unsigned short* __restrict__ ebf,
    const float* __restrict__ sq, unsigned short* __restrict__ wout,
    float* __restrict__ invrs) {
  __shared__ unsigned short Ei[64 * 64];
  __shared__ unsigned short Ej[2][128 * 64];
  int tid = threadIdx.x, lane = tid & 63, wid = tid >> 6;
  int b = blockIdx.y;
  int i0 = blockIdx.x * 64;
  const unsigned short* eb = ebf + (long)b * NN * SDIM;

  #pragma unroll
  for (int it = 0; it < 2; ++it) {
    int c = it * 256 + tid;
    int r = c >> 3, c8 = c & 7;
    gload16(eb + (long)(i0 + r) * SDIM + c8 * 8, Ei + (it * 256 + (tid & 192)) * 8);
  }
  auto stageEj = [&](int buf, int j0) {
    #pragma unroll
    for (int it = 0; it < 4; ++it) {
      int c = it * 256 + tid;
      int r = c >> 3, c8 = c & 7;
      gload16(eb + (long)(j0 + r) * SDIM + c8 * 8, &Ej[buf][(it * 256 + (tid & 192)) * 8]);
    }
  };
  stageEj(0, 0);
  __syncthreads();
  bf16x8_t afrag[2];
  #pragma unroll
  for (int s2i = 0; s2i < 2; ++s2i)
    afrag[s2i] = *(const bf16x8_t*)&Ei[(wid * 16 + (lane & 15)) * 64 + s2i * 32 + (lane >> 4) * 8];
  int rloc = wid * 16 + ((lane >> 4) << 2);
  float sqi[4];
  #pragma unroll
  for (int r = 0; r < 4; ++r) sqi[r] = sq[b * NN + i0 + rloc + r];
  float rs[4] = {0.f, 0.f, 0.f, 0.f};

  for (int jt = 0; jt < NN / 128; ++jt) {
    int cur = jt & 1;
    if (jt + 1 < NN / 128) stageEj(cur ^ 1, (jt + 1) * 128);
    int j0 = jt * 128;
    #pragma unroll
    for (int n = 0; n < 8; ++n) {
      f32x4_t g = {0.f, 0.f, 0.f, 0.f};
      #pragma unroll
      for (int s2i = 0; s2i < 2; ++s2i) {
        bf16x8_t bfr = *(const bf16x8_t*)&Ej[cur][(n * 16 + (lane & 15)) * 64 + s2i * 32 + (lane >> 4) * 8];
        g = __builtin_amdgcn_mfma_f32_16x16x32_bf16(afrag[s2i], bfr, g, 0, 0, 0);
      }
      int col = j0 + n * 16 + (lane & 15);
      float sqj = sq[b * NN + col];
      #pragma unroll
      for (int r = 0; r < 4; ++r) {
        float d2 = sqi[r] + sqj - 2.0f * g[r];
        d2 = fmaxf(d2, 0.0f);
        float w = __expf(-d2);
        unsigned short wb = f2bf(w);
        rs[r] += bf2f(wb);
        wout[(long)b * NN * NN + (long)(i0 + rloc + r) * NN + col] = wb;
      }
    }
    __syncthreads();
  }
  #pragma unroll
  for (int off = 1; off < 16; off <<= 1) {
    #pragma unroll
    for (int r = 0; r < 4; ++r) rs[r] += __shfl_xor(rs[r], off);
  }
  if ((lane & 15) == 0) {
    #pragma unroll
    for (int r = 0; r < 4; ++r) invrs[b * NN + i0 + rloc + r] = 1.0f / rs[r];
  }
}

// ==== gemm1w: SINGLE-WAVE block, 64x64 tile, BK=32, dbuf, BARRIER-FREE ========
// Each block = 1 wave; counted waits are per-wave (race-free by construction):
//   stage(t+1) issued under MFMA(t); s_waitcnt vmcnt(0) after MFMA; no barriers.
// 16 KB LDS -> 10 blocks/CU. acc 64 AGPR + ~60 VGPR -> 4 waves/SIMD eligible.
// C = A[M,K] @ BT[N,K]^T, bf16 out with bias+GELU (FF1 only).
// M%64==0, N%64==0, K%32==0.
__global__ __launch_bounds__(64, 3) void gemm1w_ff1(
    const unsigned short* __restrict__ A, const unsigned short* __restrict__ BT,
    unsigned short* __restrict__ Cout, const float* __restrict__ bias,
    int Nmat, int K) {
  __shared__ unsigned short As[2][2048];   // [buf][64*32]
  __shared__ unsigned short Bs[2][2048];
  int lane = threadIdx.x & 63;
  int lr = lane & 15, hi = lane >> 4;

  // bijective XCD-chunk swizzle on (x,y)-linear block id
  int gx = gridDim.x;
  int wg = blockIdx.y * gx + blockIdx.x;
  int nwg = gx * gridDim.y;
  if ((nwg & 7) == 0) wg = (wg & 7) * (nwg >> 3) + (wg >> 3);
  int bj = wg % gx, bi = wg / gx;
  int row0 = bi * 64, col0 = bj * 64;

  // staging source pointers: chunk ch = it*64+lane; r=ch>>2, c=ch&3;
  // content-swizzle c ^= r&3 (2-bit key, 4 chunks/row of 32 elems)
  int r4 = lane >> 2;
  int key = r4 & 3;
  int sc8 = ((lane & 3) ^ key) * 8;
  const unsigned short* pA[4];
  const unsigned short* pB[4];
  #pragma unroll
  for (int it = 0; it < 4; ++it) {
    pA[it] = A + (long)(row0 + it * 16 + r4) * K + sc8;
    pB[it] = BT + (long)(col0 + it * 16 + r4) * K + sc8;
  }

  auto stage = [&](int buf) {
    #pragma unroll
    for (int it = 0; it < 4; ++it) {
      gload16(pA[it], &As[buf][it * 512]);
      gload16(pB[it], &Bs[buf][it * 512]);
      pA[it] += 32;
      pB[it] += 32;
    }
  };

  // fragment element offsets within a [64][32] tile (swizzle-matched):
  // row ra, k-chunk hi -> ra*32 + ((hi ^ (ra&3)) * 8); ra&3 == lr&3
  int fk = lr & 3;
  int offA[4], offB[4];
  #pragma unroll
  for (int m = 0; m < 4; ++m) {
    offA[m] = (m * 16 + lr) * 32 + ((hi ^ fk) * 8);
    offB[m] = (m * 16 + lr) * 32 + ((hi ^ fk) * 8);
  }

  const f32x4_t fzero = {0.f, 0.f, 0.f, 0.f};
  f32x4_t acc[4][4];
  #pragma unroll
  for (int m = 0; m < 4; ++m)
    #pragma unroll
    for (int n = 0; n < 4; ++n) acc[m][n] = fzero;

  int nk = K >> 5;
  stage(0);
  asm volatile("s_waitcnt vmcnt(0)" ::: "memory");

  for (int t = 0; t < nk; ++t) {
    int cur = t & 1;
    bf16x8_t a[4], b[4];
    #pragma unroll
    for (int m = 0; m < 4; ++m) a[m] = *(const bf16x8_t*)&As[cur][offA[m]];
    #pragma unroll
    for (int n = 0; n < 4; ++n) b[n] = *(const bf16x8_t*)&Bs[cur][offB[n]];
    if (t + 1 < nk) stage(cur ^ 1);          // writes OTHER buf; reads above target cur
    asm volatile("s_waitcnt lgkmcnt(0)" ::: "memory");
    __builtin_amdgcn_sched_barrier(0);       // rule #18: pin MFMA after the wait
    #pragma unroll
    for (int m = 0; m < 4; ++m)
      #pragma unroll
      for (int n = 0; n < 4; ++n)
        acc[m][n] = __builtin_amdgcn_mfma_f32_16x16x32_bf16(a[m], b[n], acc[m][n], 0, 0, 0);
    __builtin_amdgcn_sched_barrier(0);       // keep vmcnt wait after MFMA cluster
    if (t + 1 < nk) asm volatile("s_waitcnt vmcnt(0)" ::: "memory");  // next buf ready
  }

  // epilogue: bias + GELU, bf16 out
  int rbase = row0 + hi * 4;
  int cbase = col0 + lr;
  float bv[4];
  #pragma unroll
  for (int n = 0; n < 4; ++n) bv[n] = bias[cbase + n * 16];
  #pragma unroll
  for (int m = 0; m < 4; ++m) {
    #pragma unroll
    for (int r = 0; r < 4; ++r) {
      int row = rbase + m * 16 + r;
      #pragma unroll
      for (int n = 0; n < 4; ++n) {
        int col = cbase + n * 16;
        Cout[(long)row * Nmat + col] = f2bf(gelu_fast(acc[m][n][r] + bv[n]));
      }
    }
  }
}

// ==== gemm97: 128x128 tile, BK=64, 256 thr (4 waves 2x2), single 32 KiB LDS ===
// 2 barriers/K-step, T2 content-swizzle, XCD swizzle; 4 blocks/CU residency.
// C = A[M,K] @ BT[N,K]^T.  M%128==0, K%64==0; Nmat<128 handled by clamp+mask.
// EPI 0: f32 out, row-scale invrs.  EPI 1: bf16 out, bias+GELU.  EPI 2: f32,
// bias + residual.
template <int EPI>
__global__ __launch_bounds__(256, 4) void gemm97(
    const unsigned short* __restrict__ A, const unsigned short* __restrict__ BT,
    void* __restrict__ Cout, const float* __restrict__ bias,
    const float* __restrict__ resid, const float* __restrict__ invrs,
    int Nmat, int K, long sA, long sB, long sC, long sR) {
  __shared__ unsigned short As[128 * 64];
  __shared__ unsigned short Bs[128 * 64];
  int tid = threadIdx.x, lane = tid & 63;
  int lr = lane & 15, hi = lane >> 4;
  int wid = tid >> 6, wr = wid >> 1, wc = wid & 1;
  int bb = blockIdx.z;

  int gx = gridDim.x;
  int wg = blockIdx.y * gx + blockIdx.x;
  int nwg = gx * gridDim.y;
  if ((nwg & 7) == 0) wg = (wg & 7) * (nwg >> 3) + (wg >> 3);
  int bj = wg % gx, bi = wg / gx;
  int row0 = bi * 128, col0 = bj * 128;

  const unsigned short* Ab = A + (long)bb * sA;
  const unsigned short* Bb = BT + (long)bb * sB;

  int rl = tid >> 3;
  int scs = ((tid & 7) ^ (rl & 7)) * 8;
  const unsigned short* pA[4];
  const unsigned short* pB[4];
  #pragma unroll
  for (int it = 0; it < 4; ++it) {
    int ra = row0 + it * 32 + rl;
    pA[it] = Ab + (long)ra * K + scs;
    int rb = col0 + it * 32 + rl;
    if (rb > Nmat - 1) rb = Nmat - 1;
    pB[it] = Bb + (long)rb * K + scs;
  }
  int dstc = (tid & 192) * 8;

  int offA[4][2], offB[4][2];
  #pragma unroll
  for (int m = 0; m < 4; ++m) {
    #pragma unroll
    for (int s = 0; s < 2; ++s) {
      int ra = wr * 64 + m * 16 + lr;
      offA[m][s] = ra * 64 + (((s * 4 + hi) ^ (ra & 7)) * 8);
      int rb = wc * 64 + m * 16 + lr;
      offB[m][s] = rb * 64 + (((s * 4 + hi) ^ (rb & 7)) * 8);
    }
  }

  const f32x4_t fzero = {0.f, 0.f, 0.f, 0.f};
  f32x4_t acc[4][4];
  #pragma unroll
  for (int m = 0; m < 4; ++m)
    #pragma unroll
    for (int n = 0; n < 4; ++n) acc[m][n] = fzero;

  int nk = K >> 6;
  for (int t = 0; t < nk; ++t) {
    #pragma unroll
    for (int it = 0; it < 4; ++it) {
      gload16(pA[it], &As[it * 2048 + dstc]);
      gload16(pB[it], &Bs[it * 2048 + dstc]);
      pA[it] += 64;
      pB[it] += 64;
    }
    __syncthreads();
    #pragma unroll
    for (int s = 0; s < 2; ++s) {
      bf16x8_t a[4], b[4];
      #pragma unroll
      for (int m = 0; m < 4; ++m) a[m] = *(const bf16x8_t*)&As[offA[m][s]];
      #pragma unroll
      for (int n = 0; n < 4; ++n) b[n] = *(const bf16x8_t*)&Bs[offB[n][s]];
      #pragma unroll
      for (int m = 0; m < 4; ++m)
        #pragma unroll
        for (int n = 0; n < 4; ++n)
          acc[m][n] = __builtin_amdgcn_mfma_f32_16x16x32_bf16(a[m], b[n], acc[m][n], 0, 0, 0);
    }
    __syncthreads();
  }

  int rbase = row0 + wr * 64 + hi * 4;
  int cbase = col0 + wc * 64 + lr;
  float bv[4];
  #pragma unroll
  for (int n = 0; n < 4; ++n)
    bv[n] = (EPI != 0 && cbase + n * 16 < Nmat) ? bias[cbase + n * 16] : 0.f;
  #pragma unroll
  for (int m = 0; m < 4; ++m) {
    #pragma unroll
    for (int r = 0; r < 4; ++r) {
      int row = rbase + m * 16 + r;
      float ir = (EPI == 0) ? invrs[(long)bb * sR + row] : 0.f;
      #pragma unroll
      for (int n = 0; n < 4; ++n) {
        int col = cbase + n * 16;
        if (col >= Nmat) continue;
        float v = acc[m][n][r];
        long cidx = (long)bb * sC + (long)row * Nmat + col;
        if (EPI == 0) {
          ((float*)Cout)[cidx] = v * ir;
        } else if (EPI == 1) {
          ((unsigned short*)Cout)[cidx] = f2bf(gelu_fast(v + bv[n]));
        } else {
          ((float*)Cout)[cidx] = v + bv[n] + resid[(long)bb * sR + (long)row * Nmat + col];
        }
      }
    }
  }
}

extern "C" void kernel_launch(void* const* d_in, const int* in_sizes, int n_in,
                              void* d_out, int out_size, void* d_ws, size_t ws_size,
                              hipStream_t stream) {
  (void)in_sizes; (void)n_in; (void)out_size; (void)ws_size;
  const float* in_z   = (const float*)d_in[0];
  const float* in_s   = (const float*)d_in[1];
  const float* lnz_sc = (const float*)d_in[2];
  const float* lnz_bi = (const float*)d_in[3];
  const float* lns_sc = (const float*)d_in[4];
  const float* lns_bi = (const float*)d_in[5];
  const float* Wz1 = (const float*)d_in[6];
  const float* bz1 = (const float*)d_in[7];
  const float* Wz2 = (const float*)d_in[8];
  const float* bz2 = (const float*)d_in[9];
  const float* Ws1 = (const float*)d_in[10];
  const float* bs1 = (const float*)d_in[11];
  const float* Ws2 = (const float*)d_in[12];
  const float* bs2 = (const float*)d_in[13];
  float* out_z = (float*)d_out;
  float* out_s = out_z + (long)ROWS * ZDIM;

  char* ws = (char*)d_ws;
  size_t off = 0;
  auto alloc = [&](size_t bytes) { void* p = ws + off; off += (bytes + 255) & ~(size_t)255; return p; };
  unsigned short* WH   = (unsigned short*)alloc((size_t)BATCH * NN * NN * 2); // w / h aliased
  unsigned short* ZT   = (unsigned short*)alloc((size_t)BATCH * ZDIM * NN * 2);
  unsigned short* XLN  = (unsigned short*)alloc((size_t)ROWS * ZDIM * 2);
  unsigned short* EBF  = (unsigned short*)alloc((size_t)ROWS * SDIM * 2);
  float* ZATT = (float*)alloc((size_t)ROWS * ZDIM * 4);
  float* ZBUF = (float*)alloc((size_t)ROWS * ZDIM * 4);
  float* SBUF = (float*)alloc((size_t)ROWS * SDIM * 4);
  float* SQ   = (float*)alloc((size_t)ROWS * 4);
  float* IRS  = (float*)alloc((size_t)ROWS * 4);
  unsigned short* W1Z = (unsigned short*)alloc((size_t)DEPTH * MLPD * ZDIM * 2);
  unsigned short* W2Z = (unsigned short*)alloc((size_t)DEPTH * ZDIM * MLPD * 2);
  unsigned short* W1S = (unsigned short*)alloc((size_t)DEPTH * MLPD * ZDIM * 2);
  unsigned short* W2S = (unsigned short*)alloc((size_t)DEPTH * SDIM * MLPD * 2);

  tconv_kernel<<<dim3(MLPD / 32, ZDIM / 32, DEPTH), dim3(32, 8), 0, stream>>>(
      Wz1, W1Z, ZDIM, MLPD, (long)ZDIM * MLPD, (long)MLPD * ZDIM);
  tconv_kernel<<<dim3(ZDIM / 32, MLPD / 32, DEPTH), dim3(32, 8), 0, stream>>>(
      Wz2, W2Z, MLPD, ZDIM, (long)MLPD * ZDIM, (long)ZDIM * MLPD);
  tconv_kernel<<<dim3(MLPD / 32, ZDIM / 32, DEPTH), dim3(32, 8), 0, stream>>>(
      Ws1, W1S, ZDIM, MLPD, (long)ZDIM * MLPD, (long)MLPD * ZDIM);
  tconv_kernel<<<dim3(SDIM / 32, MLPD / 32, DEPTH), dim3(32, 8), 0, stream>>>(
      Ws2, W2S, MLPD, SDIM, (long)MLPD * SDIM, (long)SDIM * MLPD);

  for (int L = 0; L < DEPTH; ++L) {
    const float* z_in = (L == 0) ? in_z : ZBUF;
    const float* s_in = (L == 0) ? in_s : SBUF;
    float* z_out = (L == DEPTH - 1) ? out_z : ZBUF;
    float* s_out = (L == DEPTH - 1) ? out_s : SBUF;

    conv_e_kernel<<<ROWS / 4, 256, 0, stream>>>(s_in, EBF, SQ);
    tconv_kernel<<<dim3(ZDIM / 32, NN / 32, BATCH), dim3(32, 8), 0, stream>>>(
        z_in, ZT, NN, ZDIM, (long)NN * ZDIM, (long)ZDIM * NN);
    attn_w_kernel<<<dim3(NN / 64, BATCH), 256, 0, stream>>>(EBF, SQ, WH, IRS);
    // z_att = (w @ z) / rowsum : M=NN, N=ZDIM, K=NN, batched
    gemm97<0><<<dim3(ZDIM / 128, NN / 128, BATCH), 256, 0, stream>>>(
        WH, ZT, ZATT, nullptr, nullptr, IRS,
        ZDIM, NN, (long)NN * NN, (long)ZDIM * NN, (long)NN * ZDIM, NN);
    // z-FF
    ln_kernel<<<ROWS / 4, 256, 0, stream>>>(ZATT, lnz_sc + L * ZDIM, lnz_bi + L * ZDIM, XLN);
    gemm1w_ff1<<<dim3(MLPD / 64, ROWS / 64, 1), 64, 0, stream>>>(
        XLN, W1Z + (long)L * MLPD * ZDIM, WH, bz1 + L * MLPD, MLPD, ZDIM);
    gemm97<2><<<dim3(ZDIM / 128, ROWS / 128, 1), 256, 0, stream>>>(
        WH, W2Z + (long)L * ZDIM * MLPD, z_out, bz2 + L * ZDIM, ZATT, nullptr,
        ZDIM, MLPD, 0, 0, 0, 0);
    // s-FF
    ln_kernel<<<ROWS / 4, 256, 0, stream>>>(z_out, lns_sc + L * ZDIM, lns_bi + L * ZDIM, XLN);
    gemm1w_ff1<<<dim3(MLPD / 64, ROWS / 64, 1), 64, 0, stream>>>(
        XLN, W1S + (long)L * MLPD * ZDIM, WH, bs1 + L * MLPD, MLPD, ZDIM);
    gemm97<2><<<dim3(1, ROWS / 128, 1), 256, 0, stream>>>(
        WH, W2S + (long)L * SDIM * MLPD, s_out, bs2 + L * SDIM, s_in, nullptr,
        SDIM, MLPD, 0, 0, 0, 0);
  }
}

// Round 8
// 1257.761 us; speedup vs baseline: 1.1891x; 1.1891x over previous
//
#include <hip/hip_runtime.h>
#include <stdint.h>

#define DEPTH 4
#define BATCH 8
#define NN 2048
#define ZDIM 512
#define SDIM 64
#define MLPD 2048
#define ROWS (BATCH*NN)   // 16384

typedef __bf16 bf16x8_t __attribute__((ext_vector_type(8)));
typedef float f32x4_t __attribute__((ext_vector_type(4)));
typedef unsigned short us;

#define AS1 __attribute__((address_space(1)))
#define AS3 __attribute__((address_space(3)))

__device__ __forceinline__ void gload16(const void* g, void* l) {
  __builtin_amdgcn_global_load_lds((const AS1 void*)g, (AS3 void*)l, 16, 0, 0);
}

__device__ __forceinline__ unsigned short f2bf(float f) {
  union { float f; unsigned u; } v; v.f = f;
  unsigned u = v.u;
  unsigned r = (u + 0x7fffu + ((u >> 16) & 1u)) >> 16;
  return (unsigned short)r;
}
__device__ __forceinline__ float bf2f(unsigned short h) {
  union { unsigned u; float f; } v; v.u = ((unsigned)h) << 16;
  return v.f;
}

// exact-erf GELU via Abramowitz-Stegun 7.1.26 (max abs err 1.5e-7)
__device__ __forceinline__ float gelu_fast(float x) {
  float ax = fabsf(x) * 0.70710678118654752440f;
  float t = __builtin_amdgcn_rcpf(1.0f + 0.3275911f * ax);
  float p = t * (0.254829592f + t * (-0.284496736f + t * (1.421413741f +
            t * (-1.453152027f + t * 1.061405429f))));
  float er = 1.0f - p * __expf(-ax * ax);
  float s = (x >= 0.f) ? er : -er;
  return 0.5f * x * (1.0f + s);
}

#define LGKM0() do { asm volatile("s_waitcnt lgkmcnt(0)" ::: "memory"); \
                     __builtin_amdgcn_sched_barrier(0); } while (0)

// ---- convert spatial embedding rows to bf16 + squared norms ------------------
__global__ __launch_bounds__(256) void conv_e_kernel(const float* __restrict__ s,
    unsigned short* __restrict__ ebf, float* __restrict__ sq) {
  int lane = threadIdx.x & 63;
  int row = blockIdx.x * 4 + (threadIdx.x >> 6);
  float x = s[(long)row * SDIM + lane];
  unsigned short v = f2bf(x);
  ebf[(long)row * SDIM + lane] = v;
  float xb = bf2f(v);
  float ss = xb * xb;
  #pragma unroll
  for (int off = 32; off > 0; off >>= 1) ss += __shfl_xor(ss, off);
  if (lane == 0) sq[row] = ss;
}

// ---- transpose + f32->bf16: in [R][C] f32 -> out [C][R] bf16, batched --------
__global__ __launch_bounds__(256) void tconv_kernel(const float* __restrict__ in,
    unsigned short* __restrict__ out, int R, int C, long sIn, long sOut) {
  __shared__ float tile[32][33];
  int b = blockIdx.z;
  int c0 = blockIdx.x * 32, r0 = blockIdx.y * 32;
  int tx = threadIdx.x, ty = threadIdx.y;
  const float* ib = in + (long)b * sIn;
  unsigned short* ob = out + (long)b * sOut;
  #pragma unroll
  for (int i = 0; i < 32; i += 8)
    tile[ty + i][tx] = ib[(long)(r0 + ty + i) * C + c0 + tx];
  __syncthreads();
  #pragma unroll
  for (int i = 0; i < 32; i += 8)
    ob[(long)(c0 + ty + i) * R + r0 + tx] = f2bf(tile[tx][ty + i]);
}

// ---- LayerNorm over D=512, write bf16 normalized rows ------------------------
__global__ __launch_bounds__(256) void ln_kernel(const float* __restrict__ x,
    const float* __restrict__ scale, const float* __restrict__ bias,
    unsigned short* __restrict__ y) {
  int lane = threadIdx.x & 63;
  long row = (long)blockIdx.x * 4 + (threadIdx.x >> 6);
  const float* xr = x + row * ZDIM + lane * 8;
  float4 v0 = *(const float4*)xr;
  float4 v1 = *(const float4*)(xr + 4);
  float xv[8] = {v0.x, v0.y, v0.z, v0.w, v1.x, v1.y, v1.z, v1.w};
  float s1 = 0.f, s2 = 0.f;
  #pragma unroll
  for (int k = 0; k < 8; ++k) { s1 += xv[k]; s2 += xv[k] * xv[k]; }
  #pragma unroll
  for (int off = 32; off > 0; off >>= 1) {
    s1 += __shfl_xor(s1, off);
    s2 += __shfl_xor(s2, off);
  }
  float mean = s1 * (1.0f / ZDIM);
  float var = s2 * (1.0f / ZDIM) - mean * mean;
  float rstd = rsqrtf(var + 1e-5f);
  const float* sc = scale + lane * 8;
  const float* bi = bias + lane * 8;
  alignas(16) unsigned short o[8];
  #pragma unroll
  for (int k = 0; k < 8; ++k)
    o[k] = f2bf((xv[k] - mean) * rstd * sc[k] + bi[k]);
  *(uint4*)(y + row * ZDIM + lane * 8) = *(const uint4*)o;
}

// ---- attention weights: w = exp(-max(sq_i+sq_j-2*e_i.e_j,0)), plus 1/rowsum --
// E tiles source-swizzled (T2); w stores vectorized via per-wave LDS repack.
__global__ __launch_bounds__(256) void attn_w_kernel(const unsigned short* __restrict__ ebf,
    const float* __restrict__ sq, unsigned short* __restrict__ wout,
    float* __restrict__ invrs) {
  __shared__ unsigned short Ei[4096];       // 64 x 64
  __shared__ unsigned short Ej[8192];       // 128 x 64
  __shared__ unsigned short Wt[8192];       // 4 waves x (16 x 128)
  int tid = threadIdx.x, lane = tid & 63, wid = tid >> 6;
  int lr = lane & 15, hi = lane >> 4;
  int b = blockIdx.y;
  int i0 = blockIdx.x * 64;
  const unsigned short* eb = ebf + (long)b * NN * SDIM;

  int rl = tid >> 3;                       // chunk row (within 32-row group)
  int scs = ((tid & 7) ^ (rl & 7)) * 8;    // swizzled source chunk
  int dstc = (tid & 192) * 8;

  // stage Ei (64x64): 2 its
  #pragma unroll
  for (int it = 0; it < 2; ++it)
    gload16(eb + (long)(i0 + it * 32 + rl) * SDIM + scs, &Ei[it * 2048 + dstc]);
  // stage Ej tile 0
  #pragma unroll
  for (int it = 0; it < 4; ++it)
    gload16(eb + (long)(it * 32 + rl) * SDIM + scs, &Ej[it * 2048 + dstc]);
  __syncthreads();

  // afrag: row ra = wid*16+lr, k-chunk (s*4+hi) ^ (ra&7)
  bf16x8_t afrag[2];
  int ka = lr & 7;  // (wid*16+lr)&7 == lr&7
  #pragma unroll
  for (int s = 0; s < 2; ++s)
    afrag[s] = *(const bf16x8_t*)&Ei[(wid * 16 + lr) * 64 + (((s * 4 + hi) ^ ka) * 8)];
  int rloc = wid * 16 + (hi << 2);
  float sqi[4];
  #pragma unroll
  for (int r = 0; r < 4; ++r) sqi[r] = sq[b * NN + i0 + rloc + r];
  float rs[4] = {0.f, 0.f, 0.f, 0.f};
  us* stripe = &Wt[wid * 2048];

  for (int jt = 0; jt < NN / 128; ++jt) {
    if (jt > 0) {
      __syncthreads();   // all waves done with previous Ej + Wt
      #pragma unroll
      for (int it = 0; it < 4; ++it)
        gload16(eb + (long)(jt * 128 + it * 32 + rl) * SDIM + scs, &Ej[it * 2048 + dstc]);
      __syncthreads();   // staged
    }
    int j0 = jt * 128;
    #pragma unroll
    for (int n = 0; n < 8; ++n) {
      f32x4_t g = {0.f, 0.f, 0.f, 0.f};
      #pragma unroll
      for (int s = 0; s < 2; ++s) {
        int rb = n * 16 + lr;
        bf16x8_t bfr = *(const bf16x8_t*)&Ej[rb * 64 + (((s * 4 + hi) ^ (rb & 7)) * 8)];
        g = __builtin_amdgcn_mfma_f32_16x16x32_bf16(afrag[s], bfr, g, 0, 0, 0);
      }
      float sqj = sq[b * NN + j0 + n * 16 + lr];
      #pragma unroll
      for (int r = 0; r < 4; ++r) {
        float d2 = sqi[r] + sqj - 2.0f * g[r];
        d2 = fmaxf(d2, 0.0f);
        float w = __expf(-d2);
        unsigned short wb = f2bf(w);
        rs[r] += bf2f(wb);
        int srow = (hi << 2) + r;                  // 0..15
        stripe[srow * 128 + ((n ^ (srow & 3)) * 16) + lr] = wb;
      }
    }
    LGKM0();   // own stripe writes complete
    #pragma unroll
    for (int it = 0; it < 4; ++it) {
      int seg = it * 64 + lane;
      int row = seg >> 4, c8 = seg & 15;
      int c8s = c8 ^ ((row & 3) << 1);
      uint4 v = *(const uint4*)&stripe[row * 128 + c8s * 8];
      long gi = i0 + wid * 16 + row;
      *(uint4*)&wout[(long)b * NN * NN + gi * NN + j0 + c8 * 8] = v;
    }
  }
  #pragma unroll
  for (int off = 1; off < 16; off <<= 1) {
    #pragma unroll
    for (int r = 0; r < 4; ++r) rs[r] += __shfl_xor(rs[r], off);
  }
  if (lr == 0) {
    #pragma unroll
    for (int r = 0; r < 4; ++r) invrs[b * NN + i0 + rloc + r] = 1.0f / rs[r];
  }
}

// ==== gemm24w: BM=64, BN=128, BK=64, 256 thr (4 waves of 32x64), 24 KiB LDS ===
// Single-buffer, 2 barriers/K-step; residency-driven overlap (target 6 blk/CU =
// 24 waves). T2 content-swizzle; T1 XCD swizzle. EPI1 (bf16+GELU) uses per-wave
// LDS repack -> dwordx4 stores. C = A[M,K] @ BT[N,K]^T; M%64==0,N%128==0,K%64==0.
template <int EPI>
__global__ __launch_bounds__(256, 6) void gemm24w(
    const unsigned short* __restrict__ A, const unsigned short* __restrict__ BT,
    void* __restrict__ Cout, const float* __restrict__ bias,
    const float* __restrict__ resid, const float* __restrict__ invrs,
    int Nmat, int K, long sA, long sB, long sC, long sR) {
  __shared__ unsigned short As[64 * 64];    // 8 KB
  __shared__ unsigned short Bs[128 * 64];   // 16 KB
  int tid = threadIdx.x, lane = tid & 63;
  int lr = lane & 15, hi = lane >> 4;
  int wid = tid >> 6, wr = wid >> 1, wc = wid & 1;
  int bb = blockIdx.z;

  int gx = gridDim.x;
  int wg = blockIdx.y * gx + blockIdx.x;
  int nwg = gx * gridDim.y;
  if ((nwg & 7) == 0) wg = (wg & 7) * (nwg >> 3) + (wg >> 3);
  int bj = wg % gx, bi = wg / gx;
  int row0 = bi * 64, col0 = bj * 128;

  const unsigned short* Ab = A + (long)bb * sA;
  const unsigned short* Bb = BT + (long)bb * sB;

  int rl = tid >> 3;
  int scs = ((tid & 7) ^ (rl & 7)) * 8;
  const unsigned short* pA[2];
  const unsigned short* pB[4];
  #pragma unroll
  for (int it = 0; it < 2; ++it)
    pA[it] = Ab + (long)(row0 + it * 32 + rl) * K + scs;
  #pragma unroll
  for (int it = 0; it < 4; ++it)
    pB[it] = Bb + (long)(col0 + it * 32 + rl) * K + scs;
  int dstc = (tid & 192) * 8;

  int offA[2][2], offB[4][2];
  #pragma unroll
  for (int m = 0; m < 2; ++m)
    #pragma unroll
    for (int s = 0; s < 2; ++s) {
      int ra = wr * 32 + m * 16 + lr;
      offA[m][s] = ra * 64 + (((s * 4 + hi) ^ (ra & 7)) * 8);
    }
  #pragma unroll
  for (int n = 0; n < 4; ++n)
    #pragma unroll
    for (int s = 0; s < 2; ++s) {
      int rb = wc * 64 + n * 16 + lr;
      offB[n][s] = rb * 64 + (((s * 4 + hi) ^ (rb & 7)) * 8);
    }

  const f32x4_t fzero = {0.f, 0.f, 0.f, 0.f};
  f32x4_t acc[2][4];
  #pragma unroll
  for (int m = 0; m < 2; ++m)
    #pragma unroll
    for (int n = 0; n < 4; ++n) acc[m][n] = fzero;

  int nk = K >> 6;
  for (int t = 0; t < nk; ++t) {
    #pragma unroll
    for (int it = 0; it < 2; ++it) { gload16(pA[it], &As[it * 2048 + dstc]); pA[it] += 64; }
    #pragma unroll
    for (int it = 0; it < 4; ++it) { gload16(pB[it], &Bs[it * 2048 + dstc]); pB[it] += 64; }
    __syncthreads();
    #pragma unroll
    for (int s = 0; s < 2; ++s) {
      bf16x8_t a[2], b[4];
      #pragma unroll
      for (int m = 0; m < 2; ++m) a[m] = *(const bf16x8_t*)&As[offA[m][s]];
      #pragma unroll
      for (int n = 0; n < 4; ++n) b[n] = *(const bf16x8_t*)&Bs[offB[n][s]];
      #pragma unroll
      for (int m = 0; m < 2; ++m)
        #pragma unroll
        for (int n = 0; n < 4; ++n)
          acc[m][n] = __builtin_amdgcn_mfma_f32_16x16x32_bf16(a[m], b[n], acc[m][n], 0, 0, 0);
    }
    __syncthreads();
  }

  int rbase = row0 + wr * 32 + hi * 4;
  int cbase = col0 + wc * 64 + lr;
  if (EPI == 1) {
    // GELU -> per-wave LDS stripe (32x64 bf16, XOR-swizzled) -> dwordx4 stores
    float bv[4];
    #pragma unroll
    for (int n = 0; n < 4; ++n) bv[n] = bias[cbase + n * 16];
    us* stripe = &Bs[wid * 2048];
    #pragma unroll
    for (int m = 0; m < 2; ++m) {
      #pragma unroll
      for (int r = 0; r < 4; ++r) {
        int sr = m * 16 + hi * 4 + r;          // 0..31
        #pragma unroll
        for (int n = 0; n < 4; ++n)
          stripe[sr * 64 + ((n ^ (sr & 3)) * 16) + lr] =
              f2bf(gelu_fast(acc[m][n][r] + bv[n]));
      }
    }
    LGKM0();
    unsigned short* Cb = (unsigned short*)Cout;
    #pragma unroll
    for (int it = 0; it < 4; ++it) {
      int seg = it * 64 + lane;
      int sr = seg >> 3, c8 = seg & 7;
      int c8s = c8 ^ ((sr & 3) << 1);
      uint4 v = *(const uint4*)&stripe[sr * 64 + c8s * 8];
      long row = row0 + wr * 32 + sr;
      *(uint4*)&Cb[row * Nmat + col0 + wc * 64 + c8 * 8] = v;
    }
  } else {
    #pragma unroll
    for (int m = 0; m < 2; ++m) {
      #pragma unroll
      for (int r = 0; r < 4; ++r) {
        int row = rbase + m * 16 + r;
        float ir = (EPI == 0) ? invrs[(long)bb * sR + row] : 0.f;
        #pragma unroll
        for (int n = 0; n < 4; ++n) {
          int col = cbase + n * 16;
          float v = acc[m][n][r];
          long cidx = (long)bb * sC + (long)row * Nmat + col;
          if (EPI == 0) {
            ((float*)Cout)[cidx] = v * ir;
          } else {
            ((float*)Cout)[cidx] = v + bias[col] + resid[(long)bb * sR + (long)row * Nmat + col];
          }
        }
      }
    }
  }
}

// ==== gemm97: 128x128 tile, BK=64, 256 thr (4 waves 2x2), single 32 KiB LDS ===
template <int EPI>
__global__ __launch_bounds__(256, 4) void gemm97(
    const unsigned short* __restrict__ A, const unsigned short* __restrict__ BT,
    void* __restrict__ Cout, const float* __restrict__ bias,
    const float* __restrict__ resid, const float* __restrict__ invrs,
    int Nmat, int K, long sA, long sB, long sC, long sR) {
  __shared__ unsigned short As[128 * 64];
  __shared__ unsigned short Bs[128 * 64];
  int tid = threadIdx.x, lane = tid & 63;
  int lr = lane & 15, hi = lane >> 4;
  int wid = tid >> 6, wr = wid >> 1, wc = wid & 1;
  int bb = blockIdx.z;

  int gx = gridDim.x;
  int wg = blockIdx.y * gx + blockIdx.x;
  int nwg = gx * gridDim.y;
  if ((nwg & 7) == 0) wg = (wg & 7) * (nwg >> 3) + (wg >> 3);
  int bj = wg % gx, bi = wg / gx;
  int row0 = bi * 128, col0 = bj * 128;

  const unsigned short* Ab = A + (long)bb * sA;
  const unsigned short* Bb = BT + (long)bb * sB;

  int rl = tid >> 3;
  int scs = ((tid & 7) ^ (rl & 7)) * 8;
  const unsigned short* pA[4];
  const unsigned short* pB[4];
  #pragma unroll
  for (int it = 0; it < 4; ++it) {
    int ra = row0 + it * 32 + rl;
    pA[it] = Ab + (long)ra * K + scs;
    int rb = col0 + it * 32 + rl;
    if (rb > Nmat - 1) rb = Nmat - 1;
    pB[it] = Bb + (long)rb * K + scs;
  }
  int dstc = (tid & 192) * 8;

  int offA[4][2], offB[4][2];
  #pragma unroll
  for (int m = 0; m < 4; ++m) {
    #pragma unroll
    for (int s = 0; s < 2; ++s) {
      int ra = wr * 64 + m * 16 + lr;
      offA[m][s] = ra * 64 + (((s * 4 + hi) ^ (ra & 7)) * 8);
      int rb = wc * 64 + m * 16 + lr;
      offB[m][s] = rb * 64 + (((s * 4 + hi) ^ (rb & 7)) * 8);
    }
  }

  const f32x4_t fzero = {0.f, 0.f, 0.f, 0.f};
  f32x4_t acc[4][4];
  #pragma unroll
  for (int m = 0; m < 4; ++m)
    #pragma unroll
    for (int n = 0; n < 4; ++n) acc[m][n] = fzero;

  int nk = K >> 6;
  for (int t = 0; t < nk; ++t) {
    #pragma unroll
    for (int it = 0; it < 4; ++it) {
      gload16(pA[it], &As[it * 2048 + dstc]);
      gload16(pB[it], &Bs[it * 2048 + dstc]);
      pA[it] += 64;
      pB[it] += 64;
    }
    __syncthreads();
    #pragma unroll
    for (int s = 0; s < 2; ++s) {
      bf16x8_t a[4], b[4];
      #pragma unroll
      for (int m = 0; m < 4; ++m) a[m] = *(const bf16x8_t*)&As[offA[m][s]];
      #pragma unroll
      for (int n = 0; n < 4; ++n) b[n] = *(const bf16x8_t*)&Bs[offB[n][s]];
      #pragma unroll
      for (int m = 0; m < 4; ++m)
        #pragma unroll
        for (int n = 0; n < 4; ++n)
          acc[m][n] = __builtin_amdgcn_mfma_f32_16x16x32_bf16(a[m], b[n], acc[m][n], 0, 0, 0);
    }
    __syncthreads();
  }

  int rbase = row0 + wr * 64 + hi * 4;
  int cbase = col0 + wc * 64 + lr;
  float bv[4];
  #pragma unroll
  for (int n = 0; n < 4; ++n)
    bv[n] = (EPI != 0 && cbase + n * 16 < Nmat) ? bias[cbase + n * 16] : 0.f;
  #pragma unroll
  for (int m = 0; m < 4; ++m) {
    #pragma unroll
    for (int r = 0; r < 4; ++r) {
      int row = rbase + m * 16 + r;
      float ir = (EPI == 0) ? invrs[(long)bb * sR + row] : 0.f;
      #pragma unroll
      for (int n = 0; n < 4; ++n) {
        int col = cbase + n * 16;
        if (col >= Nmat) continue;
        float v = acc[m][n][r];
        long cidx = (long)bb * sC + (long)row * Nmat + col;
        if (EPI == 0) {
          ((float*)Cout)[cidx] = v * ir;
        } else if (EPI == 1) {
          ((unsigned short*)Cout)[cidx] = f2bf(gelu_fast(v + bv[n]));
        } else {
          ((float*)Cout)[cidx] = v + bv[n] + resid[(long)bb * sR + (long)row * Nmat + col];
        }
      }
    }
  }
}

extern "C" void kernel_launch(void* const* d_in, const int* in_sizes, int n_in,
                              void* d_out, int out_size, void* d_ws, size_t ws_size,
                              hipStream_t stream) {
  (void)in_sizes; (void)n_in; (void)out_size; (void)ws_size;
  const float* in_z   = (const float*)d_in[0];
  const float* in_s   = (const float*)d_in[1];
  const float* lnz_sc = (const float*)d_in[2];
  const float* lnz_bi = (const float*)d_in[3];
  const float* lns_sc = (const float*)d_in[4];
  const float* lns_bi = (const float*)d_in[5];
  const float* Wz1 = (const float*)d_in[6];
  const float* bz1 = (const float*)d_in[7];
  const float* Wz2 = (const float*)d_in[8];
  const float* bz2 = (const float*)d_in[9];
  const float* Ws1 = (const float*)d_in[10];
  const float* bs1 = (const float*)d_in[11];
  const float* Ws2 = (const float*)d_in[12];
  const float* bs2 = (const float*)d_in[13];
  float* out_z = (float*)d_out;
  float* out_s = out_z + (long)ROWS * ZDIM;

  char* ws = (char*)d_ws;
  size_t off = 0;
  auto alloc = [&](size_t bytes) { void* p = ws + off; off += (bytes + 255) & ~(size_t)255; return p; };
  unsigned short* WH   = (unsigned short*)alloc((size_t)BATCH * NN * NN * 2); // w / h aliased
  unsigned short* ZT   = (unsigned short*)alloc((size_t)BATCH * ZDIM * NN * 2);
  unsigned short* XLN  = (unsigned short*)alloc((size_t)ROWS * ZDIM * 2);
  unsigned short* EBF  = (unsigned short*)alloc((size_t)ROWS * SDIM * 2);
  float* ZATT = (float*)alloc((size_t)ROWS * ZDIM * 4);
  float* ZBUF = (float*)alloc((size_t)ROWS * ZDIM * 4);
  float* SBUF = (float*)alloc((size_t)ROWS * SDIM * 4);
  float* SQ   = (float*)alloc((size_t)ROWS * 4);
  float* IRS  = (float*)alloc((size_t)ROWS * 4);
  unsigned short* W1Z = (unsigned short*)alloc((size_t)DEPTH * MLPD * ZDIM * 2);
  unsigned short* W2Z = (unsigned short*)alloc((size_t)DEPTH * ZDIM * MLPD * 2);
  unsigned short* W1S = (unsigned short*)alloc((size_t)DEPTH * MLPD * ZDIM * 2);
  unsigned short* W2S = (unsigned short*)alloc((size_t)DEPTH * SDIM * MLPD * 2);

  tconv_kernel<<<dim3(MLPD / 32, ZDIM / 32, DEPTH), dim3(32, 8), 0, stream>>>(
      Wz1, W1Z, ZDIM, MLPD, (long)ZDIM * MLPD, (long)MLPD * ZDIM);
  tconv_kernel<<<dim3(ZDIM / 32, MLPD / 32, DEPTH), dim3(32, 8), 0, stream>>>(
      Wz2, W2Z, MLPD, ZDIM, (long)MLPD * ZDIM, (long)ZDIM * MLPD);
  tconv_kernel<<<dim3(MLPD / 32, ZDIM / 32, DEPTH), dim3(32, 8), 0, stream>>>(
      Ws1, W1S, ZDIM, MLPD, (long)ZDIM * MLPD, (long)MLPD * ZDIM);
  tconv_kernel<<<dim3(SDIM / 32, MLPD / 32, DEPTH), dim3(32, 8), 0, stream>>>(
      Ws2, W2S, MLPD, SDIM, (long)MLPD * SDIM, (long)SDIM * MLPD);

  for (int L = 0; L < DEPTH; ++L) {
    const float* z_in = (L == 0) ? in_z : ZBUF;
    const float* s_in = (L == 0) ? in_s : SBUF;
    float* z_out = (L == DEPTH - 1) ? out_z : ZBUF;
    float* s_out = (L == DEPTH - 1) ? out_s : SBUF;

    conv_e_kernel<<<ROWS / 4, 256, 0, stream>>>(s_in, EBF, SQ);
    tconv_kernel<<<dim3(ZDIM / 32, NN / 32, BATCH), dim3(32, 8), 0, stream>>>(
        z_in, ZT, NN, ZDIM, (long)NN * ZDIM, (long)ZDIM * NN);
    attn_w_kernel<<<dim3(NN / 64, BATCH), 256, 0, stream>>>(EBF, SQ, WH, IRS);
    // z_att = (w @ z) / rowsum : M=NN, N=ZDIM, K=NN, batched
    gemm97<0><<<dim3(ZDIM / 128, NN / 128, BATCH), 256, 0, stream>>>(
        WH, ZT, ZATT, nullptr, nullptr, IRS,
        ZDIM, NN, (long)NN * NN, (long)ZDIM * NN, (long)NN * ZDIM, NN);
    // z-FF
    ln_kernel<<<ROWS / 4, 256, 0, stream>>>(ZATT, lnz_sc + L * ZDIM, lnz_bi + L * ZDIM, XLN);
    gemm24w<1><<<dim3(MLPD / 128, ROWS / 64, 1), 256, 0, stream>>>(
        XLN, W1Z + (long)L * MLPD * ZDIM, WH, bz1 + L * MLPD, nullptr, nullptr,
        MLPD, ZDIM, 0, 0, 0, 0);
    gemm24w<2><<<dim3(ZDIM / 128, ROWS / 64, 1), 256, 0, stream>>>(
        WH, W2Z + (long)L * ZDIM * MLPD, z_out, bz2 + L * ZDIM, ZATT, nullptr,
        ZDIM, MLPD, 0, 0, 0, 0);
    // s-FF
    ln_kernel<<<ROWS / 4, 256, 0, stream>>>(z_out, lns_sc + L * ZDIM, lns_bi + L * ZDIM, XLN);
    gemm24w<1><<<dim3(MLPD / 128, ROWS / 64, 1), 256, 0, stream>>>(
        XLN, W1S + (long)L * MLPD * ZDIM, WH, bs1 + L * MLPD, nullptr, nullptr,
        MLPD, ZDIM, 0, 0, 0, 0);
    gemm97<2><<<dim3(1, ROWS / 128, 1), 256, 0, stream>>>(
        WH, W2S + (long)L * SDIM * MLPD, s_out, bs2 + L * SDIM, s_in, nullptr,
        SDIM, MLPD, 0, 0, 0, 0);
  }
}

// Round 9
// 1125.146 us; speedup vs baseline: 1.3293x; 1.1179x over previous
//
#include <hip/hip_runtime.h>
#include <stdint.h>

#define DEPTH 4
#define BATCH 8
#define NN 2048
#define ZDIM 512
#define SDIM 64
#define MLPD 2048
#define ROWS (BATCH*NN)   // 16384

typedef __bf16 bf16x8_t __attribute__((ext_vector_type(8)));
typedef float f32x4_t __attribute__((ext_vector_type(4)));
typedef unsigned short us;

#define AS1 __attribute__((address_space(1)))
#define AS3 __attribute__((address_space(3)))

__device__ __forceinline__ void gload16(const void* g, void* l) {
  __builtin_amdgcn_global_load_lds((const AS1 void*)g, (AS3 void*)l, 16, 0, 0);
}

__device__ __forceinline__ unsigned short f2bf(float f) {
  union { float f; unsigned u; } v; v.f = f;
  unsigned u = v.u;
  unsigned r = (u + 0x7fffu + ((u >> 16) & 1u)) >> 16;
  return (unsigned short)r;
}
__device__ __forceinline__ float bf2f(unsigned short h) {
  union { unsigned u; float f; } v; v.u = ((unsigned)h) << 16;
  return v.f;
}

// exact-erf GELU via Abramowitz-Stegun 7.1.26 (max abs err 1.5e-7)
__device__ __forceinline__ float gelu_fast(float x) {
  float ax = fabsf(x) * 0.70710678118654752440f;
  float t = __builtin_amdgcn_rcpf(1.0f + 0.3275911f * ax);
  float p = t * (0.254829592f + t * (-0.284496736f + t * (1.421413741f +
            t * (-1.453152027f + t * 1.061405429f))));
  float er = 1.0f - p * __expf(-ax * ax);
  float s = (x >= 0.f) ? er : -er;
  return 0.5f * x * (1.0f + s);
}

#define LGKM0() do { asm volatile("s_waitcnt lgkmcnt(0)" ::: "memory"); \
                     __builtin_amdgcn_sched_barrier(0); } while (0)

// ---- convert spatial embedding rows to bf16 + squared norms ------------------
__global__ __launch_bounds__(256) void conv_e_kernel(const float* __restrict__ s,
    unsigned short* __restrict__ ebf, float* __restrict__ sq) {
  int lane = threadIdx.x & 63;
  int row = blockIdx.x * 4 + (threadIdx.x >> 6);
  float x = s[(long)row * SDIM + lane];
  unsigned short v = f2bf(x);
  ebf[(long)row * SDIM + lane] = v;
  float xb = bf2f(v);
  float ss = xb * xb;
  #pragma unroll
  for (int off = 32; off > 0; off >>= 1) ss += __shfl_xor(ss, off);
  if (lane == 0) sq[row] = ss;
}

// ---- transpose + f32->bf16: in [R][C] f32 -> out [C][R] bf16, batched --------
__global__ __launch_bounds__(256) void tconv_kernel(const float* __restrict__ in,
    unsigned short* __restrict__ out, int R, int C, long sIn, long sOut) {
  __shared__ float tile[32][33];
  int b = blockIdx.z;
  int c0 = blockIdx.x * 32, r0 = blockIdx.y * 32;
  int tx = threadIdx.x, ty = threadIdx.y;
  const float* ib = in + (long)b * sIn;
  unsigned short* ob = out + (long)b * sOut;
  #pragma unroll
  for (int i = 0; i < 32; i += 8)
    tile[ty + i][tx] = ib[(long)(r0 + ty + i) * C + c0 + tx];
  __syncthreads();
  #pragma unroll
  for (int i = 0; i < 32; i += 8)
    ob[(long)(c0 + ty + i) * R + r0 + tx] = f2bf(tile[tx][ty + i]);
}

// ---- LayerNorm over D=512, write bf16 normalized rows ------------------------
__global__ __launch_bounds__(256) void ln_kernel(const float* __restrict__ x,
    const float* __restrict__ scale, const float* __restrict__ bias,
    unsigned short* __restrict__ y) {
  int lane = threadIdx.x & 63;
  long row = (long)blockIdx.x * 4 + (threadIdx.x >> 6);
  const float* xr = x + row * ZDIM + lane * 8;
  float4 v0 = *(const float4*)xr;
  float4 v1 = *(const float4*)(xr + 4);
  float xv[8] = {v0.x, v0.y, v0.z, v0.w, v1.x, v1.y, v1.z, v1.w};
  float s1 = 0.f, s2 = 0.f;
  #pragma unroll
  for (int k = 0; k < 8; ++k) { s1 += xv[k]; s2 += xv[k] * xv[k]; }
  #pragma unroll
  for (int off = 32; off > 0; off >>= 1) {
    s1 += __shfl_xor(s1, off);
    s2 += __shfl_xor(s2, off);
  }
  float mean = s1 * (1.0f / ZDIM);
  float var = s2 * (1.0f / ZDIM) - mean * mean;
  float rstd = rsqrtf(var + 1e-5f);
  const float* sc = scale + lane * 8;
  const float* bi = bias + lane * 8;
  alignas(16) unsigned short o[8];
  #pragma unroll
  for (int k = 0; k < 8; ++k)
    o[k] = f2bf((xv[k] - mean) * rstd * sc[k] + bi[k]);
  *(uint4*)(y + row * ZDIM + lane * 8) = *(const uint4*)o;
}

// ---- attention weights, 4-way j-split: each block does 64 i-rows x 512 j-cols,
// writes w (bf16, vectorized via per-wave LDS repack) + PARTIAL rowsum
// RS[q][b*NN+i]. PV epilogue sums the 4 partials. grid (NN/64, 4, BATCH).
__global__ __launch_bounds__(256) void attn_w_kernel(const unsigned short* __restrict__ ebf,
    const float* __restrict__ sq, unsigned short* __restrict__ wout,
    float* __restrict__ RS) {
  __shared__ unsigned short Ei[4096];       // 64 x 64
  __shared__ unsigned short Ej[8192];       // 128 x 64
  __shared__ unsigned short Wt[8192];       // 4 waves x (16 x 128)
  int tid = threadIdx.x, lane = tid & 63, wid = tid >> 6;
  int lr = lane & 15, hi = lane >> 4;
  int q = blockIdx.y;
  int b = blockIdx.z;
  int i0 = blockIdx.x * 64;
  const unsigned short* eb = ebf + (long)b * NN * SDIM;

  int rl = tid >> 3;
  int scs = ((tid & 7) ^ (rl & 7)) * 8;
  int dstc = (tid & 192) * 8;

  #pragma unroll
  for (int it = 0; it < 2; ++it)
    gload16(eb + (long)(i0 + it * 32 + rl) * SDIM + scs, &Ei[it * 2048 + dstc]);
  // stage first Ej tile of this quarter
  #pragma unroll
  for (int it = 0; it < 4; ++it)
    gload16(eb + (long)(q * 512 + it * 32 + rl) * SDIM + scs, &Ej[it * 2048 + dstc]);
  __syncthreads();

  bf16x8_t afrag[2];
  int ka = lr & 7;
  #pragma unroll
  for (int s = 0; s < 2; ++s)
    afrag[s] = *(const bf16x8_t*)&Ei[(wid * 16 + lr) * 64 + (((s * 4 + hi) ^ ka) * 8)];
  int rloc = wid * 16 + (hi << 2);
  float sqi[4];
  #pragma unroll
  for (int r = 0; r < 4; ++r) sqi[r] = sq[b * NN + i0 + rloc + r];
  float rs[4] = {0.f, 0.f, 0.f, 0.f};
  us* stripe = &Wt[wid * 2048];

  for (int jj = 0; jj < 4; ++jj) {
    int j0 = q * 512 + jj * 128;
    if (jj > 0) {
      __syncthreads();
      #pragma unroll
      for (int it = 0; it < 4; ++it)
        gload16(eb + (long)(j0 + it * 32 + rl) * SDIM + scs, &Ej[it * 2048 + dstc]);
      __syncthreads();
    }
    #pragma unroll
    for (int n = 0; n < 8; ++n) {
      f32x4_t g = {0.f, 0.f, 0.f, 0.f};
      #pragma unroll
      for (int s = 0; s < 2; ++s) {
        int rb = n * 16 + lr;
        bf16x8_t bfr = *(const bf16x8_t*)&Ej[rb * 64 + (((s * 4 + hi) ^ (rb & 7)) * 8)];
        g = __builtin_amdgcn_mfma_f32_16x16x32_bf16(afrag[s], bfr, g, 0, 0, 0);
      }
      float sqj = sq[b * NN + j0 + n * 16 + lr];
      #pragma unroll
      for (int r = 0; r < 4; ++r) {
        float d2 = sqi[r] + sqj - 2.0f * g[r];
        d2 = fmaxf(d2, 0.0f);
        float w = __expf(-d2);
        unsigned short wb = f2bf(w);
        rs[r] += bf2f(wb);
        int srow = (hi << 2) + r;
        stripe[srow * 128 + ((n ^ (srow & 3)) * 16) + lr] = wb;
      }
    }
    LGKM0();
    #pragma unroll
    for (int it = 0; it < 4; ++it) {
      int seg = it * 64 + lane;
      int row = seg >> 4, c8 = seg & 15;
      int c8s = c8 ^ ((row & 3) << 1);
      uint4 v = *(const uint4*)&stripe[row * 128 + c8s * 8];
      long gi = i0 + wid * 16 + row;
      *(uint4*)&wout[(long)b * NN * NN + gi * NN + j0 + c8 * 8] = v;
    }
  }
  #pragma unroll
  for (int off = 1; off < 16; off <<= 1) {
    #pragma unroll
    for (int r = 0; r < 4; ++r) rs[r] += __shfl_xor(rs[r], off);
  }
  if (lr == 0) {
    #pragma unroll
    for (int r = 0; r < 4; ++r)
      RS[(long)q * ROWS + b * NN + i0 + rloc + r] = rs[r];
  }
}

// ==== gemm3b: 64x128 tile, BK=64, 256 thr (4 waves of 32x64), 24 KiB single buf
// Split-phase K-step: bar1(vmcnt drain, covered by prev MFMA) -> ds_read 12
// frags -> bar2 (reads complete) -> stage(t+1) into same buffer -> 16 MFMA from
// regs (covers stage latency). T2 content-swizzle; T1 XCD swizzle.
// C = A[M,K] @ BT[N,K]^T; M%64==0, K%64==0; Nmat<128 via clamp+mask.
// EPI 0: f32 out, scale by 1/sum(RS[0..3][row]).  EPI 1: bf16 out, bias+GELU
// (repack->dwordx4).  EPI 2: f32 out, bias+residual.
template <int EPI>
__global__ __launch_bounds__(256, 4) void gemm3b(
    const unsigned short* __restrict__ A, const unsigned short* __restrict__ BT,
    void* __restrict__ Cout, const float* __restrict__ bias,
    const float* __restrict__ resid, const float* __restrict__ RS,
    int Nmat, int K, long sA, long sB, long sC, long sR) {
  __shared__ unsigned short As[64 * 64];    // 8 KB
  __shared__ unsigned short Bs[128 * 64];   // 16 KB
  int tid = threadIdx.x, lane = tid & 63;
  int lr = lane & 15, hi = lane >> 4;
  int wid = tid >> 6, wr = wid >> 1, wc = wid & 1;
  int bb = blockIdx.z;

  int gx = gridDim.x;
  int wg = blockIdx.y * gx + blockIdx.x;
  int nwg = gx * gridDim.y;
  if ((nwg & 7) == 0) wg = (wg & 7) * (nwg >> 3) + (wg >> 3);
  int bj = wg % gx, bi = wg / gx;
  int row0 = bi * 64, col0 = bj * 128;

  const unsigned short* Ab = A + (long)bb * sA;
  const unsigned short* Bb = BT + (long)bb * sB;

  int rl = tid >> 3;
  int scs = ((tid & 7) ^ (rl & 7)) * 8;
  const unsigned short* pA[2];
  const unsigned short* pB[4];
  #pragma unroll
  for (int it = 0; it < 2; ++it)
    pA[it] = Ab + (long)(row0 + it * 32 + rl) * K + scs;
  #pragma unroll
  for (int it = 0; it < 4; ++it) {
    int rb = col0 + it * 32 + rl;
    if (rb > Nmat - 1) rb = Nmat - 1;   // N=64 tail: duplicate row, masked store
    pB[it] = Bb + (long)rb * K + scs;
  }
  int dstc = (tid & 192) * 8;

  int offA[2][2], offB[4][2];
  #pragma unroll
  for (int m = 0; m < 2; ++m)
    #pragma unroll
    for (int s = 0; s < 2; ++s) {
      int ra = wr * 32 + m * 16 + lr;
      offA[m][s] = ra * 64 + (((s * 4 + hi) ^ (ra & 7)) * 8);
    }
  #pragma unroll
  for (int n = 0; n < 4; ++n)
    #pragma unroll
    for (int s = 0; s < 2; ++s) {
      int rb = wc * 64 + n * 16 + lr;
      offB[n][s] = rb * 64 + (((s * 4 + hi) ^ (rb & 7)) * 8);
    }

  auto stage = [&]() {
    #pragma unroll
    for (int it = 0; it < 2; ++it) { gload16(pA[it], &As[it * 2048 + dstc]); pA[it] += 64; }
    #pragma unroll
    for (int it = 0; it < 4; ++it) { gload16(pB[it], &Bs[it * 2048 + dstc]); pB[it] += 64; }
  };

  const f32x4_t fzero = {0.f, 0.f, 0.f, 0.f};
  f32x4_t acc[2][4];
  #pragma unroll
  for (int m = 0; m < 2; ++m)
    #pragma unroll
    for (int n = 0; n < 4; ++n) acc[m][n] = fzero;

  int nk = K >> 6;
  stage();   // tile 0

  for (int t = 0; t < nk; ++t) {
    __syncthreads();   // vmcnt(0): buffer staged (drain covered by prev MFMA)
    bf16x8_t a0s0 = *(const bf16x8_t*)&As[offA[0][0]];
    bf16x8_t a1s0 = *(const bf16x8_t*)&As[offA[1][0]];
    bf16x8_t a0s1 = *(const bf16x8_t*)&As[offA[0][1]];
    bf16x8_t a1s1 = *(const bf16x8_t*)&As[offA[1][1]];
    bf16x8_t b0s0 = *(const bf16x8_t*)&Bs[offB[0][0]];
    bf16x8_t b1s0 = *(const bf16x8_t*)&Bs[offB[1][0]];
    bf16x8_t b2s0 = *(const bf16x8_t*)&Bs[offB[2][0]];
    bf16x8_t b3s0 = *(const bf16x8_t*)&Bs[offB[3][0]];
    bf16x8_t b0s1 = *(const bf16x8_t*)&Bs[offB[0][1]];
    bf16x8_t b1s1 = *(const bf16x8_t*)&Bs[offB[1][1]];
    bf16x8_t b2s1 = *(const bf16x8_t*)&Bs[offB[2][1]];
    bf16x8_t b3s1 = *(const bf16x8_t*)&Bs[offB[3][1]];
    __syncthreads();   // lgkmcnt(0) inside: all waves' reads COMPLETE
    if (t + 1 < nk) stage();   // overwrite same buffer: safe, reads done
    acc[0][0] = __builtin_amdgcn_mfma_f32_16x16x32_bf16(a0s0, b0s0, acc[0][0], 0, 0, 0);
    acc[1][0] = __builtin_amdgcn_mfma_f32_16x16x32_bf16(a1s0, b0s0, acc[1][0], 0, 0, 0);
    acc[0][1] = __builtin_amdgcn_mfma_f32_16x16x32_bf16(a0s0, b1s0, acc[0][1], 0, 0, 0);
    acc[1][1] = __builtin_amdgcn_mfma_f32_16x16x32_bf16(a1s0, b1s0, acc[1][1], 0, 0, 0);
    acc[0][2] = __builtin_amdgcn_mfma_f32_16x16x32_bf16(a0s0, b2s0, acc[0][2], 0, 0, 0);
    acc[1][2] = __builtin_amdgcn_mfma_f32_16x16x32_bf16(a1s0, b2s0, acc[1][2], 0, 0, 0);
    acc[0][3] = __builtin_amdgcn_mfma_f32_16x16x32_bf16(a0s0, b3s0, acc[0][3], 0, 0, 0);
    acc[1][3] = __builtin_amdgcn_mfma_f32_16x16x32_bf16(a1s0, b3s0, acc[1][3], 0, 0, 0);
    acc[0][0] = __builtin_amdgcn_mfma_f32_16x16x32_bf16(a0s1, b0s1, acc[0][0], 0, 0, 0);
    acc[1][0] = __builtin_amdgcn_mfma_f32_16x16x32_bf16(a1s1, b0s1, acc[1][0], 0, 0, 0);
    acc[0][1] = __builtin_amdgcn_mfma_f32_16x16x32_bf16(a0s1, b1s1, acc[0][1], 0, 0, 0);
    acc[1][1] = __builtin_amdgcn_mfma_f32_16x16x32_bf16(a1s1, b1s1, acc[1][1], 0, 0, 0);
    acc[0][2] = __builtin_amdgcn_mfma_f32_16x16x32_bf16(a0s1, b2s1, acc[0][2], 0, 0, 0);
    acc[1][2] = __builtin_amdgcn_mfma_f32_16x16x32_bf16(a1s1, b2s1, acc[1][2], 0, 0, 0);
    acc[0][3] = __builtin_amdgcn_mfma_f32_16x16x32_bf16(a0s1, b3s1, acc[0][3], 0, 0, 0);
    acc[1][3] = __builtin_amdgcn_mfma_f32_16x16x32_bf16(a1s1, b3s1, acc[1][3], 0, 0, 0);
  }

  int rbase = row0 + wr * 32 + hi * 4;
  int cbase = col0 + wc * 64 + lr;
  if (EPI == 1) {
    float bv[4];
    #pragma unroll
    for (int n = 0; n < 4; ++n) bv[n] = bias[cbase + n * 16];
    us* stripe = &Bs[wid * 2048];
    #pragma unroll
    for (int m = 0; m < 2; ++m) {
      #pragma unroll
      for (int r = 0; r < 4; ++r) {
        int sr = m * 16 + hi * 4 + r;
        #pragma unroll
        for (int n = 0; n < 4; ++n)
          stripe[sr * 64 + ((n ^ (sr & 3)) * 16) + lr] =
              f2bf(gelu_fast(acc[m][n][r] + bv[n]));
      }
    }
    LGKM0();
    unsigned short* Cb = (unsigned short*)Cout;
    #pragma unroll
    for (int it = 0; it < 4; ++it) {
      int seg = it * 64 + lane;
      int sr = seg >> 3, c8 = seg & 7;
      int c8s = c8 ^ ((sr & 3) << 1);
      uint4 v = *(const uint4*)&stripe[sr * 64 + c8s * 8];
      long row = row0 + wr * 32 + sr;
      *(uint4*)&Cb[row * Nmat + col0 + wc * 64 + c8 * 8] = v;
    }
  } else {
    #pragma unroll
    for (int m = 0; m < 2; ++m) {
      #pragma unroll
      for (int r = 0; r < 4; ++r) {
        int row = rbase + m * 16 + r;
        float ir = 0.f;
        if (EPI == 0) {
          long idx = (long)bb * sR + row;
          float den = RS[idx] + RS[ROWS + idx] + RS[2L * ROWS + idx] + RS[3L * ROWS + idx];
          ir = 1.0f / den;
        }
        #pragma unroll
        for (int n = 0; n < 4; ++n) {
          int col = cbase + n * 16;
          if (col >= Nmat) continue;
          float v = acc[m][n][r];
          long cidx = (long)bb * sC + (long)row * Nmat + col;
          if (EPI == 0) {
            ((float*)Cout)[cidx] = v * ir;
          } else {
            ((float*)Cout)[cidx] = v + bias[col] + resid[(long)bb * sR + (long)row * Nmat + col];
          }
        }
      }
    }
  }
}

extern "C" void kernel_launch(void* const* d_in, const int* in_sizes, int n_in,
                              void* d_out, int out_size, void* d_ws, size_t ws_size,
                              hipStream_t stream) {
  (void)in_sizes; (void)n_in; (void)out_size; (void)ws_size;
  const float* in_z   = (const float*)d_in[0];
  const float* in_s   = (const float*)d_in[1];
  const float* lnz_sc = (const float*)d_in[2];
  const float* lnz_bi = (const float*)d_in[3];
  const float* lns_sc = (const float*)d_in[4];
  const float* lns_bi = (const float*)d_in[5];
  const float* Wz1 = (const float*)d_in[6];
  const float* bz1 = (const float*)d_in[7];
  const float* Wz2 = (const float*)d_in[8];
  const float* bz2 = (const float*)d_in[9];
  const float* Ws1 = (const float*)d_in[10];
  const float* bs1 = (const float*)d_in[11];
  const float* Ws2 = (const float*)d_in[12];
  const float* bs2 = (const float*)d_in[13];
  float* out_z = (float*)d_out;
  float* out_s = out_z + (long)ROWS * ZDIM;

  char* ws = (char*)d_ws;
  size_t off = 0;
  auto alloc = [&](size_t bytes) { void* p = ws + off; off += (bytes + 255) & ~(size_t)255; return p; };
  unsigned short* WH   = (unsigned short*)alloc((size_t)BATCH * NN * NN * 2); // w / h aliased
  unsigned short* ZT   = (unsigned short*)alloc((size_t)BATCH * ZDIM * NN * 2);
  unsigned short* XLN  = (unsigned short*)alloc((size_t)ROWS * ZDIM * 2);
  unsigned short* EBF  = (unsigned short*)alloc((size_t)ROWS * SDIM * 2);
  float* ZATT = (float*)alloc((size_t)ROWS * ZDIM * 4);
  float* ZBUF = (float*)alloc((size_t)ROWS * ZDIM * 4);
  float* SBUF = (float*)alloc((size_t)ROWS * SDIM * 4);
  float* SQ   = (float*)alloc((size_t)ROWS * 4);
  float* RS   = (float*)alloc((size_t)4 * ROWS * 4);
  unsigned short* W1Z = (unsigned short*)alloc((size_t)DEPTH * MLPD * ZDIM * 2);
  unsigned short* W2Z = (unsigned short*)alloc((size_t)DEPTH * ZDIM * MLPD * 2);
  unsigned short* W1S = (unsigned short*)alloc((size_t)DEPTH * MLPD * ZDIM * 2);
  unsigned short* W2S = (unsigned short*)alloc((size_t)DEPTH * SDIM * MLPD * 2);

  tconv_kernel<<<dim3(MLPD / 32, ZDIM / 32, DEPTH), dim3(32, 8), 0, stream>>>(
      Wz1, W1Z, ZDIM, MLPD, (long)ZDIM * MLPD, (long)MLPD * ZDIM);
  tconv_kernel<<<dim3(ZDIM / 32, MLPD / 32, DEPTH), dim3(32, 8), 0, stream>>>(
      Wz2, W2Z, MLPD, ZDIM, (long)MLPD * ZDIM, (long)ZDIM * MLPD);
  tconv_kernel<<<dim3(MLPD / 32, ZDIM / 32, DEPTH), dim3(32, 8), 0, stream>>>(
      Ws1, W1S, ZDIM, MLPD, (long)ZDIM * MLPD, (long)MLPD * ZDIM);
  tconv_kernel<<<dim3(SDIM / 32, MLPD / 32, DEPTH), dim3(32, 8), 0, stream>>>(
      Ws2, W2S, MLPD, SDIM, (long)MLPD * SDIM, (long)SDIM * MLPD);

  for (int L = 0; L < DEPTH; ++L) {
    const float* z_in = (L == 0) ? in_z : ZBUF;
    const float* s_in = (L == 0) ? in_s : SBUF;
    float* z_out = (L == DEPTH - 1) ? out_z : ZBUF;
    float* s_out = (L == DEPTH - 1) ? out_s : SBUF;

    conv_e_kernel<<<ROWS / 4, 256, 0, stream>>>(s_in, EBF, SQ);
    tconv_kernel<<<dim3(ZDIM / 32, NN / 32, BATCH), dim3(32, 8), 0, stream>>>(
        z_in, ZT, NN, ZDIM, (long)NN * ZDIM, (long)ZDIM * NN);
    attn_w_kernel<<<dim3(NN / 64, 4, BATCH), 256, 0, stream>>>(EBF, SQ, WH, RS);
    // z_att = (w @ z) / rowsum : M=NN, N=ZDIM, K=NN, batched
    gemm3b<0><<<dim3(ZDIM / 128, NN / 64, BATCH), 256, 0, stream>>>(
        WH, ZT, ZATT, nullptr, nullptr, RS,
        ZDIM, NN, (long)NN * NN, (long)ZDIM * NN, (long)NN * ZDIM, NN);
    // z-FF
    ln_kernel<<<ROWS / 4, 256, 0, stream>>>(ZATT, lnz_sc + L * ZDIM, lnz_bi + L * ZDIM, XLN);
    gemm3b<1><<<dim3(MLPD / 128, ROWS / 64, 1), 256, 0, stream>>>(
        XLN, W1Z + (long)L * MLPD * ZDIM, WH, bz1 + L * MLPD, nullptr, nullptr,
        MLPD, ZDIM, 0, 0, 0, 0);
    gemm3b<2><<<dim3(ZDIM / 128, ROWS / 64, 1), 256, 0, stream>>>(
        WH, W2Z + (long)L * ZDIM * MLPD, z_out, bz2 + L * ZDIM, ZATT, nullptr,
        ZDIM, MLPD, 0, 0, 0, 0);
    // s-FF
    ln_kernel<<<ROWS / 4, 256, 0, stream>>>(z_out, lns_sc + L * ZDIM, lns_bi + L * ZDIM, XLN);
    gemm3b<1><<<dim3(MLPD / 128, ROWS / 64, 1), 256, 0, stream>>>(
        XLN, W1S + (long)L * MLPD * ZDIM, WH, bs1 + L * MLPD, nullptr, nullptr,
        MLPD, ZDIM, 0, 0, 0, 0);
    gemm3b<2><<<dim3(1, ROWS / 64, 1), 256, 0, stream>>>(
        WH, W2S + (long)L * SDIM * MLPD, s_out, bs2 + L * SDIM, s_in, nullptr,
        SDIM, MLPD, 0, 0, 0, 0);
  }
}